// Round 5
// baseline (88.406 us; speedup 1.0000x reference)
//
#include <hip/hip_runtime.h>

// Shapes fixed by the reference:
//   x_LL : (8, 32, 128, 128)      f32
//   x    : (8, 4, 32, 128, 128)   f32  (channel 0 unused)
//   y    : (8, 32, 256, 256)      f32
//   out  : (8, 160, 256, 256)     f32  = cat(LL, LH, HL, HH, y) on axis 1
//
// out[b, sel*32+d, 2i+p, 2j+q] = src[b, d, i, j] * K[sel][p][q]   (sel<4)
// out[b, 128+d,    h,    w   ] = y[b, d, h, w]                    (sel==4)
//
// R5: identical structure to R3 (best so far: one source row per wave,
// two output rows), but WITHOUT nontemporal hints — A/B test whether nt
// load/store path was costing the ~15% gap to the copy ceiling.

#define DD 32
#define H_IN 128
#define W_IN 128
#define H2 256
#define W2 256

typedef float f32x4 __attribute__((ext_vector_type(4)));
typedef float f32x2 __attribute__((ext_vector_type(2)));

__global__ __launch_bounds__(256) void haar_iwt_cat_kernel(
    const float* __restrict__ xLL,
    const float* __restrict__ x,
    const float* __restrict__ y,
    float*       __restrict__ out)
{
    const unsigned tid  = threadIdx.x;
    const unsigned lane = tid & 63u;
    // wave-unit u = ((b*5 + sel)*32 + d)*128 + i   — all wave-uniform
    const unsigned u = blockIdx.x * 4u + (tid >> 6);

    const unsigned i = u & (H_IN - 1u);
    unsigned t = u >> 7;                 // (b*5 + sel)*32 + d
    const unsigned d = t & (DD - 1u);
    t >>= 5;                             // b*5 + sel, < 40
    const unsigned b   = t / 5u;
    const unsigned sel = t - b * 5u;

    const unsigned c = (sel == 4u) ? (128u + d) : (sel * 32u + d);
    float* orow = out + (((size_t)(b * 160u + c) * H2 + 2u * i) * W2);
    f32x4* o0 = ((f32x4*)orow) + lane;
    f32x4* o1 = ((f32x4*)(orow + W2)) + lane;

    if (sel == 4u) {
        const float* yrow = y + (((size_t)(b * DD + d) * H2 + 2u * i) * W2);
        const f32x4 v0 = ((const f32x4*)yrow)[lane];
        const f32x4 v1 = ((const f32x4*)(yrow + W2))[lane];
        *o0 = v0;
        *o1 = v1;
        return;
    }

    const float* src = (sel == 0u)
        ? xLL + ((size_t)(b * DD + d) * H_IN + i) * W_IN
        : x   + ((size_t)((b * 4u + sel) * DD + d) * H_IN + i) * W_IN;
    const f32x2 v = ((const f32x2*)src)[lane];

    // K[sel] rows: (k00,k01) for p=0, (k10,k11) for p=1
    float k00, k01, k10, k11;
    switch (sel) {
        case 0u: k00 =  0.5f; k01 =  0.5f; k10 =  0.5f; k11 =  0.5f; break; // LL
        case 1u: k00 = -0.5f; k01 =  0.5f; k10 = -0.5f; k11 =  0.5f; break; // LH
        case 2u: k00 = -0.5f; k01 = -0.5f; k10 =  0.5f; k11 =  0.5f; break; // HL
        default: k00 =  0.5f; k01 = -0.5f; k10 = -0.5f; k11 =  0.5f; break; // HH
    }

    f32x4 r0, r1;
    r0.x = v.x * k00; r0.y = v.x * k01; r0.z = v.y * k00; r0.w = v.y * k01;
    r1.x = v.x * k10; r1.y = v.x * k11; r1.z = v.y * k10; r1.w = v.y * k11;
    *o0 = r0;
    *o1 = r1;
}

extern "C" void kernel_launch(void* const* d_in, const int* in_sizes, int n_in,
                              void* d_out, int out_size, void* d_ws, size_t ws_size,
                              hipStream_t stream) {
    const float* xLL = (const float*)d_in[0];
    const float* x   = (const float*)d_in[1];
    const float* y   = (const float*)d_in[2];
    float*       out = (float*)d_out;

    // wave-units: 8 b * 5 sel * 32 d * 128 i = 163,840; 4 waves per block
    const int grid  = 163840 / 4;   // 40,960 blocks
    const int block = 256;
    haar_iwt_cat_kernel<<<grid, block, 0, stream>>>(xLL, x, y, out);
}

// Round 6
// 87.852 us; speedup vs baseline: 1.0063x; 1.0063x over previous
//
#include <hip/hip_runtime.h>

// Shapes fixed by the reference:
//   x_LL : (8, 32, 128, 128)      f32
//   x    : (8, 4, 32, 128, 128)   f32  (channel 0 unused)
//   y    : (8, 32, 256, 256)      f32
//   out  : (8, 160, 256, 256)     f32  = cat(LL, LH, HL, HH, y) on axis 1
//
// out[b, sel*32+d, 2i+p, 2j+q] = src[b, d, i, j] * K[sel][p][q]   (sel<4)
// out[b, 128+d,    h,    w   ] = y[b, d, h, w]                    (sel==4)
//
// R6: R5 structure, but CACHED loads + NON-TEMPORAL stores.
// Rationale: timed graph-replays reuse the same inputs (134 MB used, fits
// the 256 MB Infinity Cache). nt stores (no-allocate / evict-first) keep
// the 336 MB output stream from evicting the input set; cached loads let
// inputs stay L3-resident across replays -> reads served from MALL,
// HBM handles (mostly) the write stream only.

#define DD 32
#define H_IN 128
#define W_IN 128
#define H2 256
#define W2 256

typedef float f32x4 __attribute__((ext_vector_type(4)));
typedef float f32x2 __attribute__((ext_vector_type(2)));

__global__ __launch_bounds__(256) void haar_iwt_cat_kernel(
    const float* __restrict__ xLL,
    const float* __restrict__ x,
    const float* __restrict__ y,
    float*       __restrict__ out)
{
    const unsigned tid  = threadIdx.x;
    const unsigned lane = tid & 63u;
    // wave-unit u = ((b*5 + sel)*32 + d)*128 + i   — all wave-uniform
    const unsigned u = blockIdx.x * 4u + (tid >> 6);

    const unsigned i = u & (H_IN - 1u);
    unsigned t = u >> 7;                 // (b*5 + sel)*32 + d
    const unsigned d = t & (DD - 1u);
    t >>= 5;                             // b*5 + sel, < 40
    const unsigned b   = t / 5u;
    const unsigned sel = t - b * 5u;

    const unsigned c = (sel == 4u) ? (128u + d) : (sel * 32u + d);
    float* orow = out + (((size_t)(b * 160u + c) * H2 + 2u * i) * W2);
    f32x4* o0 = ((f32x4*)orow) + lane;
    f32x4* o1 = ((f32x4*)(orow + W2)) + lane;

    if (sel == 4u) {
        const float* yrow = y + (((size_t)(b * DD + d) * H2 + 2u * i) * W2);
        const f32x4 v0 = ((const f32x4*)yrow)[lane];        // cached load
        const f32x4 v1 = ((const f32x4*)(yrow + W2))[lane]; // cached load
        __builtin_nontemporal_store(v0, o0);
        __builtin_nontemporal_store(v1, o1);
        return;
    }

    const float* src = (sel == 0u)
        ? xLL + ((size_t)(b * DD + d) * H_IN + i) * W_IN
        : x   + ((size_t)((b * 4u + sel) * DD + d) * H_IN + i) * W_IN;
    const f32x2 v = ((const f32x2*)src)[lane];              // cached load

    // K[sel] rows: (k00,k01) for p=0, (k10,k11) for p=1
    float k00, k01, k10, k11;
    switch (sel) {
        case 0u: k00 =  0.5f; k01 =  0.5f; k10 =  0.5f; k11 =  0.5f; break; // LL
        case 1u: k00 = -0.5f; k01 =  0.5f; k10 = -0.5f; k11 =  0.5f; break; // LH
        case 2u: k00 = -0.5f; k01 = -0.5f; k10 =  0.5f; k11 =  0.5f; break; // HL
        default: k00 =  0.5f; k01 = -0.5f; k10 = -0.5f; k11 =  0.5f; break; // HH
    }

    f32x4 r0, r1;
    r0.x = v.x * k00; r0.y = v.x * k01; r0.z = v.y * k00; r0.w = v.y * k01;
    r1.x = v.x * k10; r1.y = v.x * k11; r1.z = v.y * k10; r1.w = v.y * k11;
    __builtin_nontemporal_store(r0, o0);
    __builtin_nontemporal_store(r1, o1);
}

extern "C" void kernel_launch(void* const* d_in, const int* in_sizes, int n_in,
                              void* d_out, int out_size, void* d_ws, size_t ws_size,
                              hipStream_t stream) {
    const float* xLL = (const float*)d_in[0];
    const float* x   = (const float*)d_in[1];
    const float* y   = (const float*)d_in[2];
    float*       out = (float*)d_out;

    // wave-units: 8 b * 5 sel * 32 d * 128 i = 163,840; 4 waves per block
    const int grid  = 163840 / 4;   // 40,960 blocks
    const int block = 256;
    haar_iwt_cat_kernel<<<grid, block, 0, stream>>>(xLL, x, y, out);
}